// Round 5
// baseline (956.861 us; speedup 1.0000x reference)
//
#include <hip/hip_runtime.h>
#include <cstdint>
#include <cstddef>

// ---------------------------------------------------------------------------
// GatedLatticeLayer on MI355X.  B=16 S=512 W=5 H=512 E=256 V=100000.
// MROWS = B*S = 8192.
//
// Round 11: ONE ordinary (graph-capturable) mega-kernel, grid 512 = 2
// blocks/CU guaranteed co-resident by __launch_bounds__(256,2) (LDS 32KB -> 5
// blocks/CU cap; waves 8/CU; VGPR<=256).  Phases separated by a device-scope
// spin barrier (atomicAdd + __hip_atomic_load AGENT scope + s_sleep, 50ms
// timeout valve).  Barrier counters live in the memset cnts block, so every
// graph replay (and every rocprof counter replay) resets them.
//   P0 prep (1104 vblocks): X->fp16, lmr, weight transposes, bias dots,
//      mask partition, gemmA (Breg = Acat@Whq^T staged from fp32; R8-validated)
//   P1 gemmB (960 vblocks): y<4: s0, y4-7: hv, y8+: P   (R7-validated body)
//   P2 attn (2048 vblocks): fused gather/scores/softmax/aggregate
//   P3 gemmC (512 vblocks): out = sc4 epilogue + Ebar @ WvT^T (128x64 tiles)
// R9 (cooperative API) silently failed under graph capture; this replaces the
// API, not the (validated) phase bodies.
// ---------------------------------------------------------------------------

typedef unsigned short u16;
typedef _Float16 f16;
typedef __attribute__((ext_vector_type(8))) f16 f16x8;
typedef __attribute__((ext_vector_type(4))) float f32x4;

#define SS 512
#define NBLK 512

struct KArgs {
  const float *X, *Wg, *bg, *Wh, *Wb, *Wm, *We, *bb, *bm, *be, *bh;
  const int *masks, *begins, *blens, *middles, *mlens, *ends, *elens;
  const float *emb;
  u16 *Xh; float *lmr; float *s0c;
  u16 *Breg, *WvT;
  float *bcat, *u, *cbuf;
  int *idx, *perm, *cnts;
  u16 *HPb; float4 *sc4; u16 *Ebar;
  float *out;
};

static __device__ __forceinline__ u16 f2h(float x) {
  f16 h = (f16)x;
  return __builtin_bit_cast(u16, h);
}
static __device__ __forceinline__ float h2f(u16 h) {
  return (float)__builtin_bit_cast(f16, h);
}
static __device__ __forceinline__ float sigm(float x) { return 1.f / (1.f + __expf(-x)); }

static __device__ __forceinline__ void gl2lds(const u16* g, u16* l) {
  __builtin_amdgcn_global_load_lds(
      (const __attribute__((address_space(1))) unsigned int*)g,
      (__attribute__((address_space(3))) unsigned int*)l, 16, 0, 0);
}

// device-scope spin barrier; ctr must be zeroed before launch.
static __device__ __forceinline__ void gbar(int* ctr) {
  __syncthreads();
  __threadfence();
  if (threadIdx.x == 0) {
    __hip_atomic_fetch_add(ctr, 1, __ATOMIC_RELEASE, __HIP_MEMORY_SCOPE_AGENT);
    long long t0 = (long long)__builtin_amdgcn_s_memrealtime();
    while (__hip_atomic_load(ctr, __ATOMIC_ACQUIRE, __HIP_MEMORY_SCOPE_AGENT) < NBLK) {
      __builtin_amdgcn_s_sleep(16);
      // ~50ms at 100MHz realtime clock: safety valve (wrong answer, not hang)
      if ((long long)__builtin_amdgcn_s_memrealtime() - t0 > 5000000LL) break;
    }
  }
  __syncthreads();
  __threadfence();
}

// ---------------- P0 prep body ---------------------------------------------
// [0,64):      WhvT -> Breg rows 512..1023 (fp16)
// [64,160):    WvT (512x768 fp16)
// [160,516):   wave dots: bcat[512+n]=bcomb, u, cb, bcat[0:512) copy
// [516,1028):  X -> fp16 + lmr (+ s0 zero)
// [1028,1060): mask partition -> idx/perm (cnts pre-zeroed via memsetAsync)
// [1060,1104): gemmA: Breg[M rows 0..511; Wcomb rows 1024..1919]
static __device__ void prep_body(int b, const KArgs& A_, char* smem_raw) {
  float* shmem = (float*)smem_raw;
  u16* As = (u16*)smem_raw;
  u16* Bs = (u16*)(smem_raw + 16384);
#define TI(r, c) shmem[(r)*65 + (c)]
  const int t = threadIdx.x;
  if (b < 64) {
    int k0 = (b & 7) * 64;
    int n0 = (b >> 3) * 64;
#pragma unroll
    for (int i = 0; i < 16; i++) {
      int li = i * 256 + t; int r = li >> 6, c = li & 63;
      TI(r, c) = A_.Wh[(size_t)(k0 + r) * 1536 + 1024 + n0 + c];
    }
    __syncthreads();
#pragma unroll
    for (int i = 0; i < 16; i++) {
      int li = i * 256 + t; int r = li >> 6, c = li & 63;
      A_.Breg[(size_t)(512 + n0 + r) * 512 + k0 + c] = f2h(TI(c, r));
    }
  } else if (b < 160) {
    int idx2 = b - 64;                  // [0,96)
    int ty = idx2 >> 5;
    int rem = idx2 & 31;
    int c0 = (rem & 3) * 64;
    int n0 = (rem >> 2) * 64;
    const float* Wsrc = ty == 0 ? A_.Wb : ty == 1 ? A_.Wm : A_.We;
#pragma unroll
    for (int i = 0; i < 16; i++) {
      int li = i * 256 + t; int r = li >> 6, c = li & 63;
      TI(r, c) = Wsrc[(size_t)(c0 + r) * 1024 + 512 + n0 + c];
    }
    __syncthreads();
#pragma unroll
    for (int i = 0; i < 16; i++) {
      int li = i * 256 + t; int r = li >> 6, c = li & 63;
      A_.WvT[(size_t)(n0 + r) * 768 + ty * 256 + c0 + c] = f2h(TI(c, r));
    }
  } else if (b < 516) {
    // wave-parallel dots: one wave per output scalar.
    const int lane = t & 63;
    const int widx = (b - 160) * 4 + (t >> 6);   // [0,1424)
    const int c = lane * 8;
    const float* bh = A_.bh;
    if (widx < 896) {
      int n = widx;
      float acc = 0.f;
      if (n < 771) {
        const float* src;
        if (n < 768) {
          int ty = n >> 8, ce = n & 255;
          src = (ty == 0 ? A_.Wb : ty == 1 ? A_.Wm : A_.We) + (size_t)ce * 1024 + c;
        } else {
          int ty = n - 768;
          src = (ty == 0 ? A_.bb : ty == 1 ? A_.bm : A_.be) + c;
        }
        float4 a0 = *(const float4*)src;
        float4 a1 = *(const float4*)(src + 4);
        float4 b0 = *(const float4*)(bh + c);
        float4 b1 = *(const float4*)(bh + c + 4);
        acc = a0.x * b0.x + a0.y * b0.y + a0.z * b0.z + a0.w * b0.w +
              a1.x * b1.x + a1.y * b1.y + a1.z * b1.z + a1.w * b1.w;
      }
#pragma unroll
      for (int o = 32; o > 0; o >>= 1) acc += __shfl_xor(acc, o);
      if (lane == 0) A_.bcat[512 + n] = acc;
    } else if (widx < 1408) {
      int k = widx - 896;
      const float* wr = A_.Wh + (size_t)k * 1536;
      float4 a0 = *(const float4*)(wr + c);
      float4 a1 = *(const float4*)(wr + c + 4);
      float4 a2 = *(const float4*)(wr + 512 + c);
      float4 a3 = *(const float4*)(wr + 512 + c + 4);
      float4 b0 = *(const float4*)(bh + 512 + c);
      float4 b1 = *(const float4*)(bh + 512 + c + 4);
      float4 b2 = *(const float4*)(bh + c);
      float4 b3 = *(const float4*)(bh + c + 4);
      float acc = a0.x * b0.x + a0.y * b0.y + a0.z * b0.z + a0.w * b0.w +
                  a1.x * b1.x + a1.y * b1.y + a1.z * b1.z + a1.w * b1.w +
                  a2.x * b2.x + a2.y * b2.y + a2.z * b2.z + a2.w * b2.w +
                  a3.x * b3.x + a3.y * b3.y + a3.z * b3.z + a3.w * b3.w;
#pragma unroll
      for (int o = 32; o > 0; o >>= 1) acc += __shfl_xor(acc, o);
      if (lane == 0) A_.u[k] = acc;
    } else if (widx == 1408) {
      float4 b0 = *(const float4*)(bh + c);
      float4 b1 = *(const float4*)(bh + c + 4);
      float4 b2 = *(const float4*)(bh + 512 + c);
      float4 b3 = *(const float4*)(bh + 512 + c + 4);
      float acc = b0.x * b2.x + b0.y * b2.y + b0.z * b2.z + b0.w * b2.w +
                  b1.x * b3.x + b1.y * b3.y + b1.z * b3.z + b1.w * b3.w;
#pragma unroll
      for (int o = 32; o > 0; o >>= 1) acc += __shfl_xor(acc, o);
      if (lane == 0) A_.cbuf[0] = acc;
    } else if (widx < 1417) {
      int i = (widx - 1409) * 64 + lane;   // [0,512)
      A_.bcat[i] = bh[1024 + i];
    }
  } else if (b < 1028) {
    // X -> fp16  +  lmr  (+ s0 zero)
    const int xb = b - 516;              // [0,512)
    if (xb < 32) A_.s0c[xb * 256 + t] = 0.f;
    for (int i = t; i < 4608; i += 256) shmem[i] = A_.Wg[i];
    __syncthreads();
    const int lane = t & 63, wid = t >> 6;
#pragma unroll
    for (int it = 0; it < 4; it++) {
      int pos = xb * 16 + it * 4 + wid;
      const float* x = A_.X + (size_t)pos * 512 + lane * 8;
      float4 x0 = *(const float4*)x;
      float4 x1 = *(const float4*)(x + 4);
      float xs[8] = {x0.x, x0.y, x0.z, x0.w, x1.x, x1.y, x1.z, x1.w};
      ushort4 h0, h1;
      h0.x = f2h(xs[0]); h0.y = f2h(xs[1]); h0.z = f2h(xs[2]); h0.w = f2h(xs[3]);
      h1.x = f2h(xs[4]); h1.y = f2h(xs[5]); h1.z = f2h(xs[6]); h1.w = f2h(xs[7]);
      ((ushort4*)A_.Xh)[pos * 128 + lane * 2] = h0;
      ((ushort4*)A_.Xh)[pos * 128 + lane * 2 + 1] = h1;
      float p[9];
#pragma unroll
      for (int c = 0; c < 9; c++) p[c] = 0.f;
      const float* wrow = shmem + (lane * 8) * 9;
#pragma unroll
      for (int j = 0; j < 8; j++)
#pragma unroll
        for (int c = 0; c < 9; c++) p[c] += xs[j] * wrow[j * 9 + c];
#pragma unroll
      for (int c = 0; c < 9; c++)
#pragma unroll
        for (int o = 32; o > 0; o >>= 1) p[c] += __shfl_xor(p[c], o);
      if (lane == 0) {
#pragma unroll
        for (int c = 0; c < 9; c++) A_.lmr[(size_t)pos * 9 + c] = p[c] + A_.bg[c];
      }
    }
  } else if (b < 1060) {
    // mask partition (cnts[0..1] pre-zeroed on stream)
    const int lane = t & 63;
    const int pos = (b - 1028) * 256 + t;
    bool is0 = A_.masks[pos] == 0;
    unsigned long long bal = __ballot(is0);
    unsigned long long below = (lane == 0) ? 0ull : (~0ull >> (64 - lane));
    int rank0 = __popcll(bal & below);
    int rank1 = __popcll((~bal) & below);
    int n0w = __popcll(bal);
    int base0 = 0, base1 = 0;
    if (lane == 0) {
      base0 = atomicAdd(&A_.cnts[0], n0w);
      base1 = atomicAdd(&A_.cnts[1], 64 - n0w);
    }
    base0 = __shfl(base0, 0);
    base1 = __shfl(base1, 0);
    int slot = is0 ? (base0 + rank0) : (8191 - (base1 + rank1));
    A_.perm[pos] = slot;
    A_.idx[slot] = pos;
  } else {
    // ---- gemmA: Breg[M | Wcomb] = Acat @ Whq^T, staged from fp32 ----------
    const int b2 = b - 1060;             // [0,44)
    const int m0 = (b2 % 11) * 128;
    const int n0 = (b2 / 11) * 128;
    const int lane = t & 63;
    const int wid = t >> 6;
    const int row = t >> 2;              // 0..63
    const int koff = (t & 3) * 8;
    const int lds0 = row * 32 + koff;
    const int lds1 = 2048 + lds0;

    auto asrc = [&](int r) -> const float* {
      if (r < 512) return A_.Wh + (size_t)r * 1536 + 512;
      int n = r - 512;
      if (n < 768)
        return (n < 256 ? A_.Wb : n < 512 ? A_.Wm : A_.We) + (size_t)(n & 255) * 1024;
      if (n < 771) return (n == 768 ? A_.bb : n == 769 ? A_.bm : A_.be);
      return nullptr;
    };
    const float* pa0 = asrc(m0 + row);
    const float* pa1 = asrc(m0 + 64 + row);
    const float* pb0 = A_.Wh + (size_t)(n0 + row) * 1536;
    const float* pb1 = A_.Wh + (size_t)(n0 + 64 + row) * 1536;

    const int wm = (wid & 1) * 64;
    const int wn = (wid >> 1) * 64;
    const int fr = lane & 15;
    const int kq = (lane >> 4) * 8;

    f32x4 acc[4][4];
#pragma unroll
    for (int i = 0; i < 4; i++)
#pragma unroll
      for (int j = 0; j < 4; j++) acc[i][j] = (f32x4){0.f, 0.f, 0.f, 0.f};

    auto cvt8 = [&](const float* p, int col) -> f16x8 {
      f16x8 h{};
      if (p) {
        float4 v0 = *(const float4*)(p + col);
        float4 v1 = *(const float4*)(p + col + 4);
        h[0] = (f16)v0.x; h[1] = (f16)v0.y; h[2] = (f16)v0.z; h[3] = (f16)v0.w;
        h[4] = (f16)v1.x; h[5] = (f16)v1.y; h[6] = (f16)v1.z; h[7] = (f16)v1.w;
      }
      return h;
    };
    auto STAGE = [&](int kb, int buf) {
      *(f16x8*)&As[buf * 4096 + lds0] = cvt8(pa0, kb + koff);
      *(f16x8*)&As[buf * 4096 + lds1] = cvt8(pa1, kb + koff);
      *(f16x8*)&Bs[buf * 4096 + lds0] = cvt8(pb0, kb + koff);
      *(f16x8*)&Bs[buf * 4096 + lds1] = cvt8(pb1, kb + koff);
    };
    auto COMPUTE = [&](int buf) {
      f16x8 av[4], bv[4];
#pragma unroll
      for (int i = 0; i < 4; i++) {
        av[i] = *(const f16x8*)&As[buf * 4096 + (wm + i * 16 + fr) * 32 + kq];
        bv[i] = *(const f16x8*)&Bs[buf * 4096 + (wn + i * 16 + fr) * 32 + kq];
      }
#pragma unroll
      for (int mt = 0; mt < 4; mt++)
#pragma unroll
        for (int nt = 0; nt < 4; nt++)
          acc[mt][nt] = __builtin_amdgcn_mfma_f32_16x16x32_f16(
              av[mt], bv[nt], acc[mt][nt], 0, 0, 0);
    };

    STAGE(0, 0);
    __syncthreads();
    int buf = 0;
    for (int ki = 0; ki < 15; ++ki) {     // K=512 -> 16 panels of 32
      STAGE((ki + 1) * 32, buf ^ 1);
      COMPUTE(buf);
      __syncthreads();
      buf ^= 1;
    }
    COMPUTE(buf);

    const int r0 = (lane >> 4) * 4;
#pragma unroll
    for (int mt = 0; mt < 4; mt++)
#pragma unroll
      for (int nt = 0; nt < 4; nt++) {
        int col = n0 + wn + nt * 16 + fr;
#pragma unroll
        for (int r = 0; r < 4; r++) {
          int orow0 = m0 + wm + mt * 16 + r0 + r;
          int orow = orow0 < 512 ? orow0 : orow0 + 512;  // Wcomb -> 1024..1919
          A_.Breg[(size_t)orow * 512 + col] = f2h(acc[mt][nt][r]);
        }
      }
  }
#undef TI
}

// ---------------- P1/P3 GEMM body, double-buffered BK=32 --------------------
// MODE 0 (gemmB, 64x15 vblocks): A=Xh, Bt=Breg, K=512
// MODE 2 (gemmC, 64x8 vblocks): A=Ebar, Bt=WvT, K=768, BN=64
template <int MODE>
static __device__ void gemm_body(int bx, int by, const KArgs& A_, char* smem_raw) {
  constexpr int BROWS = (MODE == 2) ? 64 : 128;
  constexpr int NT = (MODE == 2) ? 2 : 4;
  constexpr int Kdim = (MODE == 2) ? 768 : 512;
  u16* As = (u16*)smem_raw;                       // 16 KB
  u16* Bs = (u16*)(smem_raw + 16384);             // <= 16 KB
  const u16* Amat = (MODE == 0) ? A_.Xh : A_.Ebar;
  const u16* Bt = (MODE == 0) ? A_.Breg : A_.WvT;

  const int t = threadIdx.x;
  const int lane = t & 63;
  const int wid = t >> 6;
  const int m0 = bx * 128;
  const int n0 = by * BROWS;

  bool remap = false;
  if constexpr (MODE == 0) {
    const int cnt0 = A_.cnts[0];
    if (by < 4) {
      if (m0 >= cnt0) return;          // group0 only
      remap = true;
    } else if (by >= 8) {
      if (m0 + 128 <= cnt0) return;    // group1 only
      remap = true;
    }
  }

  int ra0 = m0 + (t >> 2), ra1 = m0 + 64 + (t >> 2);
  if (MODE == 0 && remap) { ra0 = A_.idx[ra0]; ra1 = A_.idx[ra1]; }
  const int rb0 = n0 + (t >> 2), rb1 = n0 + 64 + (t >> 2);
  const int koff = (t & 3) * 8;
  const int lds0 = (t >> 2) * 32 + koff;
  const int lds1 = 2048 + lds0;

  const int wm = (wid & 1) * 64;
  const int wn = (wid >> 1) * (NT * 16);
  const int fr = lane & 15;
  const int kq = (lane >> 4) * 8;

  f32x4 acc[4][NT];
#pragma unroll
  for (int i = 0; i < 4; i++)
#pragma unroll
    for (int j = 0; j < NT; j++) acc[i][j] = (f32x4){0.f, 0.f, 0.f, 0.f};

  auto STAGE = [&](int kb, int buf) {
    gl2lds(&Amat[(size_t)ra0 * Kdim + kb], &As[buf * 4096 + lds0]);
    gl2lds(&Amat[(size_t)ra1 * Kdim + kb], &As[buf * 4096 + lds1]);
    gl2lds(&Bt[(size_t)rb0 * Kdim + kb], &Bs[buf * (BROWS * 32) + lds0]);
    if constexpr (BROWS == 128)
      gl2lds(&Bt[(size_t)rb1 * Kdim + kb], &Bs[buf * (BROWS * 32) + lds1]);
  };
  auto COMPUTE = [&](int buf) {
    f16x8 av[4], bv[NT];
#pragma unroll
    for (int i = 0; i < 4; i++)
      av[i] = *(const f16x8*)&As[buf * 4096 + (wm + i * 16 + fr) * 32 + kq];
#pragma unroll
    for (int j = 0; j < NT; j++)
      bv[j] = *(const f16x8*)&Bs[buf * (BROWS * 32) + (wn + j * 16 + fr) * 32 + kq];
#pragma unroll
    for (int mt = 0; mt < 4; mt++)
#pragma unroll
      for (int nt = 0; nt < NT; nt++)
        acc[mt][nt] = __builtin_amdgcn_mfma_f32_16x16x32_f16(
            av[mt], bv[nt], acc[mt][nt], 0, 0, 0);
  };

  STAGE(koff, 0);
  __syncthreads();
  constexpr int nk = Kdim >> 5;
  int buf = 0;
  for (int ki = 0; ki < nk - 1; ++ki) {
    STAGE((ki + 1) * 32 + koff, buf ^ 1);
    COMPUTE(buf);
    __syncthreads();
    buf ^= 1;
  }
  COMPUTE(buf);

  const int r0 = (lane >> 4) * 4;
  if constexpr (MODE == 0) {
    if (by < 4) {
      float pl[4][4];
      int xrow[4][4];
#pragma unroll
      for (int mt = 0; mt < 4; mt++)
#pragma unroll
        for (int r = 0; r < 4; r++) {
          pl[mt][r] = 0.f;
          xrow[mt][r] = A_.idx[m0 + wm + mt * 16 + r0 + r];
        }
#pragma unroll
      for (int mt = 0; mt < 4; mt++)
#pragma unroll
        for (int nt = 0; nt < 4; nt++) {
          int col = n0 + wn + nt * 16 + fr;
          float bv2 = A_.u[col];
#pragma unroll
          for (int r = 0; r < 4; r++)
            pl[mt][r] += (acc[mt][nt][r] + bv2) *
                         h2f(A_.Xh[(size_t)xrow[mt][r] * 512 + col]);
        }
#pragma unroll
      for (int mt = 0; mt < 4; mt++)
#pragma unroll
        for (int r = 0; r < 4; r++) {
          float p = pl[mt][r];
          p += __shfl_xor(p, 1);
          p += __shfl_xor(p, 2);
          p += __shfl_xor(p, 4);
          p += __shfl_xor(p, 8);
          if (fr == r) {
            int slot = m0 + wm + mt * 16 + r0 + r;
            atomicAdd(&A_.s0c[slot], p);
          }
        }
      return;
    }
    if (by < 8) {
#pragma unroll
      for (int mt = 0; mt < 4; mt++)
#pragma unroll
        for (int nt = 0; nt < 4; nt++) {
          int col = n0 - 512 + wn + nt * 16 + fr;
          float bv2 = A_.bcat[col];
#pragma unroll
          for (int r = 0; r < 4; r++) {
            int row = m0 + wm + mt * 16 + r0 + r;
            A_.HPb[(size_t)row * 1408 + col] = f2h(acc[mt][nt][r] + bv2);
          }
        }
    } else {
#pragma unroll
      for (int mt = 0; mt < 4; mt++)
#pragma unroll
        for (int nt = 0; nt < 4; nt++) {
          int pcol = n0 - 1024 + wn + nt * 16 + fr;
          float bv2 = A_.bcat[512 + pcol];
#pragma unroll
          for (int r = 0; r < 4; r++) {
            int slot = m0 + wm + mt * 16 + r0 + r;
            A_.HPb[(size_t)slot * 1408 + 512 + pcol] = f2h(acc[mt][nt][r] + bv2);
          }
        }
    }
  } else {
#pragma unroll
    for (int mt = 0; mt < 4; mt++)
#pragma unroll
      for (int nt = 0; nt < NT; nt++) {
        int col = n0 + wn + nt * 16 + fr;
        float b0 = A_.bb[512 + col];
        float b1 = A_.bm[512 + col];
        float b2 = A_.be[512 + col];
#pragma unroll
        for (int r = 0; r < 4; r++) {
          int row = m0 + wm + mt * 16 + r0 + r;
          float4 s = A_.sc4[row];
          float hv = h2f(A_.HPb[(size_t)row * 1408 + col]);
          A_.out[(size_t)row * 512 + col] =
              s.x * hv + s.y * b0 + s.z * b1 + s.w * b2 + acc[mt][nt][r];
        }
      }
  }
}

// ---------------- P2 attn body ---------------------------------------------
static __device__ void attn_body(int vb, const KArgs& A_) {
  const int t = threadIdx.x;
  const int lane = t & 63;
  const int wid = t >> 6;
  const int pos = vb * 4 + wid;
  const int mask = A_.masks[pos];
  const int slot = A_.perm[pos];
  u16* erow = A_.Ebar + (size_t)pos * 768;

  int l0 = min(A_.blens[pos], 5), l1 = min(A_.mlens[pos], 5), l2 = min(A_.elens[pos], 5);
  int nv = l0 + l1 + l2;

  if (mask == 0) {
    float s0 = A_.s0c[slot] + A_.cbuf[0];
    int ninv = 15 - nv;
    float w0;
    if (ninv == 0) {
      w0 = 1.f;
    } else {
      float Mx = fmaxf(s0, 0.f);
      float e0 = __expf(s0 - Mx);
      w0 = e0 / (e0 + (float)ninv * __expf(-Mx));
    }
    if (lane == 0) A_.sc4[pos] = make_float4(w0, 0.f, 0.f, 0.f);
    ushort4 zz; zz.x = zz.y = zz.z = zz.w = 0;
    *(ushort4*)(erow + 0 * 256 + lane * 4) = zz;
    *(ushort4*)(erow + 1 * 256 + lane * 4) = zz;
    *(ushort4*)(erow + 2 * 256 + lane * 4) = zz;
  } else {
    const int s = pos & (SS - 1);
    float g[3];
    if (s == 0 || s == SS - 1) {
      g[0] = 1.f; g[1] = 0.f; g[2] = 1.f;
    } else {
      const float* p0 = A_.lmr + (size_t)(pos - 1) * 9;
      const float* p1 = A_.lmr + (size_t)pos * 9;
      const float* p2 = A_.lmr + (size_t)(pos + 1) * 9;
      g[0] = sigm(p0[0] + p1[3] + p2[6]);
      g[1] = sigm(p0[1] + p1[4] + p2[7]);
      g[2] = sigm(p0[2] + p1[5] + p2[8]);
    }
    const bool deg = (nv == 15);
    int l[3] = {l0, l1, l2};
    if (deg) { l[0] = 0; l[1] = 0; l[2] = 0; }

    float4 Pt[3];
    float qb[3];
    if (!deg) {
      const u16* prow = A_.HPb + (size_t)slot * 1408 + 512;
#pragma unroll
      for (int ty = 0; ty < 3; ty++) {
        ushort4 pu = *(const ushort4*)(prow + ty * 256 + lane * 4);
        Pt[ty].x = h2f(pu.x); Pt[ty].y = h2f(pu.y);
        Pt[ty].z = h2f(pu.z); Pt[ty].w = h2f(pu.w);
        qb[ty] = h2f(prow[768 + ty]);
      }
    }
    const int* idxp[3];
    idxp[0] = A_.begins + (size_t)pos * 5;
    idxp[1] = A_.middles + (size_t)pos * 5;
    idxp[2] = A_.ends + (size_t)pos * 5;

    float4 ev[3][5];
    float scv[3][5];
    float Mx = deg ? 0.f : -3.0e38f;
#pragma unroll
    for (int ty = 0; ty < 3; ty++) {
#pragma unroll
      for (int w = 0; w < 5; w++) {
        bool act = (w >= l[ty]);      // wave-uniform
        if (act) {
          ev[ty][w] = *(const float4*)(A_.emb + (size_t)idxp[ty][w] * 256 + lane * 4);
          float sv = 0.f;
          if (!deg) {
            float4 e = ev[ty][w];
            float d = Pt[ty].x * e.x + Pt[ty].y * e.y + Pt[ty].z * e.z + Pt[ty].w * e.w;
#pragma unroll
            for (int o = 32; o > 0; o >>= 1) d += __shfl_xor(d, o);
            sv = g[ty] * (d + qb[ty]);
          }
          scv[ty][w] = sv;
          Mx = fmaxf(Mx, sv);
        }
      }
    }
    float wts0 = deg ? 1.f : 0.f;
    float zs = wts0;
    float wts[3][5];
#pragma unroll
    for (int ty = 0; ty < 3; ty++)
#pragma unroll
      for (int w = 0; w < 5; w++) {
        bool act = (w >= l[ty]);
        float wv = act ? __expf(scv[ty][w] - Mx) : 0.f;
        wts[ty][w] = wv;
        zs += wv;
      }
    float inv = 1.f / zs;
    float alpha[3];
#pragma unroll
    for (int ty = 0; ty < 3; ty++) {
      float ax = 0.f, ay = 0.f, az = 0.f, aw = 0.f, asum = 0.f;
#pragma unroll
      for (int w = 0; w < 5; w++) {
        if (w >= l[ty]) {
          float wk = wts[ty][w];
          asum += wk;
          ax += wk * ev[ty][w].x;
          ay += wk * ev[ty][w].y;
          az += wk * ev[ty][w].z;
          aw += wk * ev[ty][w].w;
        }
      }
      float sg = g[ty] * inv;
      alpha[ty] = sg * asum;
      ushort4 h;
      h.x = f2h(ax * sg); h.y = f2h(ay * sg); h.z = f2h(az * sg); h.w = f2h(aw * sg);
      *(ushort4*)(erow + ty * 256 + lane * 4) = h;
    }
    if (lane == 0) A_.sc4[pos] = make_float4(wts0 * inv, alpha[0], alpha[1], alpha[2]);
  }
}

// ---------------- mega kernel (ordinary launch, spin barriers) --------------
__global__ __launch_bounds__(256, 2) void mega(KArgs a) {
  __shared__ __align__(16) char smem[32768];
  const int gsz = gridDim.x;           // 512
  // P0: prep (+gemmA)
  for (int vb = blockIdx.x; vb < 1104; vb += gsz) {
    prep_body(vb, a, smem);
    __syncthreads();                   // LDS reuse across vblocks
  }
  gbar(&a.cnts[2]);
  // P1: gemmB
  for (int vb = blockIdx.x; vb < 960; vb += gsz) {
    __syncthreads();                   // LDS reuse across vblocks
    gemm_body<0>(vb & 63, vb >> 6, a, smem);
  }
  gbar(&a.cnts[3]);
  // P2: attn
  for (int vb = blockIdx.x; vb < 2048; vb += gsz) attn_body(vb, a);
  gbar(&a.cnts[4]);
  // P3: gemmC
  for (int vb = blockIdx.x; vb < 512; vb += gsz) {
    __syncthreads();
    gemm_body<2>(vb & 63, vb >> 6, a, smem);
  }
}

// ---------------------------------------------------------------------------
extern "C" void kernel_launch(void* const* d_in, const int* in_sizes, int n_in,
                              void* d_out, int out_size, void* d_ws, size_t ws_size,
                              hipStream_t stream) {
  char* ws = (char*)d_ws;
  size_t off = 0;
  auto alloc = [&](size_t bytes) -> char* {
    char* p = ws + off;
    off += (bytes + 255) & ~(size_t)255;
    return p;
  };
  KArgs a;
  a.X = (const float*)d_in[0];
  a.masks = (const int*)d_in[1];
  a.begins = (const int*)d_in[2];
  a.blens = (const int*)d_in[3];
  a.middles = (const int*)d_in[4];
  a.mlens = (const int*)d_in[5];
  a.ends = (const int*)d_in[6];
  a.elens = (const int*)d_in[7];
  a.emb = (const float*)d_in[8];
  a.Wh = (const float*)d_in[9];
  a.bh = (const float*)d_in[10];
  a.Wb = (const float*)d_in[11];
  a.bb = (const float*)d_in[12];
  a.Wm = (const float*)d_in[13];
  a.bm = (const float*)d_in[14];
  a.We = (const float*)d_in[15];
  a.be = (const float*)d_in[16];
  a.Wg = (const float*)d_in[17];
  a.bg = (const float*)d_in[18];
  a.out = (float*)d_out;

  a.Xh = (u16*)alloc((size_t)8192 * 512 * 2);
  a.Breg = (u16*)alloc((size_t)1920 * 512 * 2);    // [M | WhvT | Wcomb]
  a.WvT = (u16*)alloc((size_t)512 * 768 * 2);
  a.HPb = (u16*)alloc((size_t)8192 * 1408 * 2);    // [hv fp16 | P fp16]
  a.lmr = (float*)alloc((size_t)8192 * 9 * 4);
  a.s0c = (float*)alloc((size_t)8192 * 4);
  a.bcat = (float*)alloc((size_t)1408 * 4);
  a.u = (float*)alloc((size_t)512 * 4);
  a.cbuf = (float*)alloc((size_t)4);
  a.sc4 = (float4*)alloc((size_t)8192 * 4 * 4);
  a.Ebar = (u16*)alloc((size_t)8192 * 768 * 2);
  a.idx = (int*)alloc((size_t)8192 * 4);
  a.perm = (int*)alloc((size_t)8192 * 4);
  a.cnts = (int*)alloc((size_t)256);
  if (off > ws_size) return;  // fail loudly (output stays poisoned)

  // zero partition counters (cnts[0..1]) + phase barriers (cnts[2..4])
  hipMemsetAsync(a.cnts, 0, 32, stream);
  mega<<<NBLK, 256, 0, stream>>>(a);
}

// Round 6
// 277.532 us; speedup vs baseline: 3.4478x; 3.4478x over previous
//
#include <hip/hip_runtime.h>
#include <cstdint>
#include <cstddef>

// ---------------------------------------------------------------------------
// GatedLatticeLayer on MI355X.  B=16 S=512 W=5 H=512 E=256 V=100000.
// MROWS = B*S = 8192.
//
// Round 12 = R10 (best, 275us) + gemmA merged into prep WITHOUT R8's
// occupancy tax:
//   - gemmA becomes 176 prep blocks with 64x64 tiles (2x2 MFMA/wave ->
//     16 acc VGPRs vs 64), single-buffered BK=32 in 8KB of the existing
//     18KB LDS (no 32KB bump), staged directly from fp32 inputs.
//   - removes: gemmA dispatch + gap, 512 Acat/Whq copy blocks, 4.4MB
//     intermediates.  Bit-identical K-chunk order -> identical numerics.
// R11 mega-kernel diagnosis: pipeline is latency/occupancy-bound (MfmaUtil
// 0.9%, HBM 2%, total HBM traffic 130MB); occupancy is the currency.
//
// Pipeline (4 launches + 8B memset):
//   prep_all: WhvT/WvT transposes, bias dots, X->fp16 + lmr, mask partition,
//             gemmA (Breg[M|Wcomb] = Acat @ Whq^T)
//   gemmB:    y<4: s0 (group0), y4-7: hv (all), y8+: P (group1)
//   attn:     fused gather/scores/softmax/aggregate
//   gemmC:    out = w0*hv + sum_t a_t*bv_t + Ebar @ WvT^T  (128x64 tiles)
// ---------------------------------------------------------------------------

typedef unsigned short u16;
typedef _Float16 f16;
typedef __attribute__((ext_vector_type(8))) f16 f16x8;
typedef __attribute__((ext_vector_type(4))) float f32x4;

#define MROWS 8192
#define SS 512

static __device__ __forceinline__ u16 f2h(float x) {
  f16 h = (f16)x;
  return __builtin_bit_cast(u16, h);
}
static __device__ __forceinline__ float h2f(u16 h) {
  return (float)__builtin_bit_cast(f16, h);
}
static __device__ __forceinline__ float sigm(float x) { return 1.f / (1.f + __expf(-x)); }

static __device__ __forceinline__ void gl2lds(const u16* g, u16* l) {
  __builtin_amdgcn_global_load_lds(
      (const __attribute__((address_space(1))) unsigned int*)g,
      (__attribute__((address_space(3))) unsigned int*)l, 16, 0, 0);
}

// ---------------- merged prep ----------------------------------------------
// [0,64):      WhvT -> Breg rows 512..1023 (fp16)
// [64,160):    WvT (512x768 fp16)
// [160,516):   wave dots: bcat[512+n]=bcomb, u, cb, bcat[0:512) copy
// [516,1028):  X -> fp16 + lmr (+ s0 zero)
// [1028,1060): mask partition -> idx/perm (cnts pre-zeroed via memsetAsync)
// [1060,1236): gemmA 64x64 tiles: Breg[M rows 0..511; Wcomb rows 1024..1919]
//              = Acat @ Whq^T, staged directly from fp32 (no intermediates).
__global__ __launch_bounds__(256) void prep_all(
    const float* __restrict__ X, const float* __restrict__ Wg,
    const float* __restrict__ bg, const float* __restrict__ Wh,
    const float* __restrict__ Wb, const float* __restrict__ Wm,
    const float* __restrict__ We, const float* __restrict__ bb,
    const float* __restrict__ bm, const float* __restrict__ be,
    const float* __restrict__ bh, const int* __restrict__ masks,
    u16* __restrict__ Xh, float* __restrict__ lmr, float* __restrict__ s0,
    u16* __restrict__ Breg, u16* __restrict__ WvT, float* __restrict__ bcat,
    float* __restrict__ u, float* __restrict__ cbuf, int* __restrict__ idx,
    int* __restrict__ perm, int* __restrict__ cnts) {
  __shared__ __align__(16) char smem_raw[18432];   // 4608 floats
  float* shmem = (float*)smem_raw;
#define TI(r, c) shmem[(r)*65 + (c)]
  const int b = blockIdx.x;
  const int t = threadIdx.x;
  if (b < 64) {
    int k0 = (b & 7) * 64;
    int n0 = (b >> 3) * 64;
#pragma unroll
    for (int i = 0; i < 16; i++) {
      int li = i * 256 + t; int r = li >> 6, c = li & 63;
      TI(r, c) = Wh[(size_t)(k0 + r) * 1536 + 1024 + n0 + c];
    }
    __syncthreads();
#pragma unroll
    for (int i = 0; i < 16; i++) {
      int li = i * 256 + t; int r = li >> 6, c = li & 63;
      Breg[(size_t)(512 + n0 + r) * 512 + k0 + c] = f2h(TI(c, r));
    }
  } else if (b < 160) {
    int idx2 = b - 64;                  // [0,96)
    int ty = idx2 >> 5;
    int rem = idx2 & 31;
    int c0 = (rem & 3) * 64;
    int n0 = (rem >> 2) * 64;
    const float* Wsrc = ty == 0 ? Wb : ty == 1 ? Wm : We;
#pragma unroll
    for (int i = 0; i < 16; i++) {
      int li = i * 256 + t; int r = li >> 6, c = li & 63;
      TI(r, c) = Wsrc[(size_t)(c0 + r) * 1024 + 512 + n0 + c];
    }
    __syncthreads();
#pragma unroll
    for (int i = 0; i < 16; i++) {
      int li = i * 256 + t; int r = li >> 6, c = li & 63;
      WvT[(size_t)(n0 + r) * 768 + ty * 256 + c0 + c] = f2h(TI(c, r));
    }
  } else if (b < 516) {
    // wave-parallel dots: one wave per output scalar.
    const int lane = t & 63;
    const int widx = (b - 160) * 4 + (t >> 6);   // [0,1424)
    const int c = lane * 8;
    if (widx < 896) {
      int n = widx;
      float acc = 0.f;
      if (n < 771) {
        const float* src;
        if (n < 768) {
          int ty = n >> 8, ce = n & 255;
          src = (ty == 0 ? Wb : ty == 1 ? Wm : We) + (size_t)ce * 1024 + c;
        } else {
          int ty = n - 768;
          src = (ty == 0 ? bb : ty == 1 ? bm : be) + c;
        }
        float4 a0 = *(const float4*)src;
        float4 a1 = *(const float4*)(src + 4);
        float4 b0 = *(const float4*)(bh + c);
        float4 b1 = *(const float4*)(bh + c + 4);
        acc = a0.x * b0.x + a0.y * b0.y + a0.z * b0.z + a0.w * b0.w +
              a1.x * b1.x + a1.y * b1.y + a1.z * b1.z + a1.w * b1.w;
      }
#pragma unroll
      for (int o = 32; o > 0; o >>= 1) acc += __shfl_xor(acc, o);
      if (lane == 0) bcat[512 + n] = acc;
    } else if (widx < 1408) {
      int k = widx - 896;
      const float* wr = Wh + (size_t)k * 1536;
      float4 a0 = *(const float4*)(wr + c);
      float4 a1 = *(const float4*)(wr + c + 4);
      float4 a2 = *(const float4*)(wr + 512 + c);
      float4 a3 = *(const float4*)(wr + 512 + c + 4);
      float4 b0 = *(const float4*)(bh + 512 + c);
      float4 b1 = *(const float4*)(bh + 512 + c + 4);
      float4 b2 = *(const float4*)(bh + c);
      float4 b3 = *(const float4*)(bh + c + 4);
      float acc = a0.x * b0.x + a0.y * b0.y + a0.z * b0.z + a0.w * b0.w +
                  a1.x * b1.x + a1.y * b1.y + a1.z * b1.z + a1.w * b1.w +
                  a2.x * b2.x + a2.y * b2.y + a2.z * b2.z + a2.w * b2.w +
                  a3.x * b3.x + a3.y * b3.y + a3.z * b3.z + a3.w * b3.w;
#pragma unroll
      for (int o = 32; o > 0; o >>= 1) acc += __shfl_xor(acc, o);
      if (lane == 0) u[k] = acc;
    } else if (widx == 1408) {
      float4 b0 = *(const float4*)(bh + c);
      float4 b1 = *(const float4*)(bh + c + 4);
      float4 b2 = *(const float4*)(bh + 512 + c);
      float4 b3 = *(const float4*)(bh + 512 + c + 4);
      float acc = b0.x * b2.x + b0.y * b2.y + b0.z * b2.z + b0.w * b2.w +
                  b1.x * b3.x + b1.y * b3.y + b1.z * b3.z + b1.w * b3.w;
#pragma unroll
      for (int o = 32; o > 0; o >>= 1) acc += __shfl_xor(acc, o);
      if (lane == 0) cbuf[0] = acc;
    } else if (widx < 1417) {
      int i = (widx - 1409) * 64 + lane;   // [0,512)
      bcat[i] = bh[1024 + i];
    }
  } else if (b < 1028) {
    // X -> fp16  +  lmr  (+ s0 zero)
    const int xb = b - 516;              // [0,512)
    if (xb < 32) s0[xb * 256 + t] = 0.f;
    for (int i = t; i < 4608; i += 256) shmem[i] = Wg[i];
    __syncthreads();
    const int lane = t & 63, wid = t >> 6;
#pragma unroll
    for (int it = 0; it < 4; it++) {
      int pos = xb * 16 + it * 4 + wid;
      const float* x = X + (size_t)pos * 512 + lane * 8;
      float4 x0 = *(const float4*)x;
      float4 x1 = *(const float4*)(x + 4);
      float xs[8] = {x0.x, x0.y, x0.z, x0.w, x1.x, x1.y, x1.z, x1.w};
      ushort4 h0, h1;
      h0.x = f2h(xs[0]); h0.y = f2h(xs[1]); h0.z = f2h(xs[2]); h0.w = f2h(xs[3]);
      h1.x = f2h(xs[4]); h1.y = f2h(xs[5]); h1.z = f2h(xs[6]); h1.w = f2h(xs[7]);
      ((ushort4*)Xh)[pos * 128 + lane * 2] = h0;
      ((ushort4*)Xh)[pos * 128 + lane * 2 + 1] = h1;
      float p[9];
#pragma unroll
      for (int c = 0; c < 9; c++) p[c] = 0.f;
      const float* wrow = shmem + (lane * 8) * 9;
#pragma unroll
      for (int j = 0; j < 8; j++)
#pragma unroll
        for (int c = 0; c < 9; c++) p[c] += xs[j] * wrow[j * 9 + c];
#pragma unroll
      for (int c = 0; c < 9; c++)
#pragma unroll
        for (int o = 32; o > 0; o >>= 1) p[c] += __shfl_xor(p[c], o);
      if (lane == 0) {
#pragma unroll
        for (int c = 0; c < 9; c++) lmr[(size_t)pos * 9 + c] = p[c] + bg[c];
      }
    }
  } else if (b < 1060) {
    // mask partition (cnts[0..1] pre-zeroed on stream)
    const int lane = t & 63;
    const int pos = (b - 1028) * 256 + t;
    bool is0 = masks[pos] == 0;
    unsigned long long bal = __ballot(is0);
    unsigned long long below = (lane == 0) ? 0ull : (~0ull >> (64 - lane));
    int rank0 = __popcll(bal & below);
    int rank1 = __popcll((~bal) & below);
    int n0w = __popcll(bal);
    int base0 = 0, base1 = 0;
    if (lane == 0) {
      base0 = atomicAdd(&cnts[0], n0w);
      base1 = atomicAdd(&cnts[1], 64 - n0w);
    }
    base0 = __shfl(base0, 0);
    base1 = __shfl(base1, 0);
    int slot = is0 ? (base0 + rank0) : (8191 - (base1 + rank1));
    perm[pos] = slot;
    idx[slot] = pos;
  } else {
    // ---- gemmA 64x64 tiles: Breg[M | Wcomb] = Acat @ Whq^T ----------------
    // A row r: r<512 -> Wh[r, 512..1024) (Whk);  r=512+n:
    //   n<768 -> W{b,m,e}[n&255, 0..512); n in [768,771) -> b{b,m,e}[0..512);
    //   n>=771 -> zeros.
    // B row c: Wh[c, 0..512) (Whq).  Out rows <512 direct; >=512 remapped +512.
    const int b2 = b - 1060;             // [0,176)
    const int m0 = (b2 % 22) * 64;
    const int n0 = (b2 / 22) * 64;
    const int lane = t & 63;
    const int wid = t >> 6;
    u16* As = (u16*)smem_raw;            // 4 KB (64x32 f16)
    u16* Bs = (u16*)(smem_raw + 4096);   // 4 KB
    const int srow = t >> 2;             // 0..63
    const int koff = (t & 3) * 8;
    const int lds = srow * 32 + koff;

    auto asrc = [&](int r) -> const float* {
      if (r < 512) return Wh + (size_t)r * 1536 + 512;
      int n = r - 512;
      if (n < 768)
        return (n < 256 ? Wb : n < 512 ? Wm : We) + (size_t)(n & 255) * 1024;
      if (n < 771) return (n == 768 ? bb : n == 769 ? bm : be);
      return nullptr;
    };
    const float* pa = asrc(m0 + srow);
    const float* pb = Wh + (size_t)(n0 + srow) * 1536;

    const int wm = (wid & 1) * 32;
    const int wn = (wid >> 1) * 32;
    const int fr = lane & 15;
    const int kq = (lane >> 4) * 8;

    f32x4 acc[2][2];
#pragma unroll
    for (int i = 0; i < 2; i++)
#pragma unroll
      for (int j = 0; j < 2; j++) acc[i][j] = (f32x4){0.f, 0.f, 0.f, 0.f};

    auto cvt8 = [&](const float* p, int col) -> f16x8 {
      f16x8 h{};
      if (p) {
        float4 v0 = *(const float4*)(p + col);
        float4 v1 = *(const float4*)(p + col + 4);
        h[0] = (f16)v0.x; h[1] = (f16)v0.y; h[2] = (f16)v0.z; h[3] = (f16)v0.w;
        h[4] = (f16)v1.x; h[5] = (f16)v1.y; h[6] = (f16)v1.z; h[7] = (f16)v1.w;
      }
      return h;
    };

    for (int ki = 0; ki < 16; ++ki) {    // K=512, BK=32, single-buffered
      __syncthreads();
      *(f16x8*)&As[lds] = cvt8(pa, ki * 32 + koff);
      *(f16x8*)&Bs[lds] = cvt8(pb, ki * 32 + koff);
      __syncthreads();
      f16x8 av[2], bv[2];
#pragma unroll
      for (int i = 0; i < 2; i++) {
        av[i] = *(const f16x8*)&As[(wm + i * 16 + fr) * 32 + kq];
        bv[i] = *(const f16x8*)&Bs[(wn + i * 16 + fr) * 32 + kq];
      }
#pragma unroll
      for (int mt = 0; mt < 2; mt++)
#pragma unroll
        for (int nt = 0; nt < 2; nt++)
          acc[mt][nt] = __builtin_amdgcn_mfma_f32_16x16x32_f16(
              av[mt], bv[nt], acc[mt][nt], 0, 0, 0);
    }

    const int r0 = (lane >> 4) * 4;
#pragma unroll
    for (int mt = 0; mt < 2; mt++)
#pragma unroll
      for (int nt = 0; nt < 2; nt++) {
        int col = n0 + wn + nt * 16 + fr;
#pragma unroll
        for (int r = 0; r < 4; r++) {
          int orow0 = m0 + wm + mt * 16 + r0 + r;
          int orow = orow0 < 512 ? orow0 : orow0 + 512;  // Wcomb -> 1024..1919
          Breg[(size_t)orow * 512 + col] = f2h(acc[mt][nt][r]);
        }
      }
  }
#undef TI
}

// ---------------- unified fp16 MFMA GEMM (BK=64 as 2x BK=32 panels) ---------
// 128xBN tile, 4 waves (2x2).  MODE 0: BN=128 (4x4 MFMA/wave);
// MODE 2: BN=64 (4x2 MFMA/wave, grid 64x8 -> 2 blocks/CU).
// MODE 0 (gemmB, 64x15):
//   y<4:  group0 slots; A rows = Xh[idx[slot]]; s0c[slot] += rowdot(.+u, Xh)
//   y4-7: all rows pos space; HPb[row*1408 + col] = f2h(acc + bcat[col])
//   y>=8: group1 slots; A rows = Xh[idx[slot]]; HPb[slot*1408+512+pcol]
// MODE 2 (gemmC, 64x8):  out = sc4.x*hv + sc4.{y,z,w}.bv + acc
template <int MODE>
__global__ __launch_bounds__(256) void gemm_k(
    const u16* __restrict__ A, const u16* __restrict__ Bt,
    const float* __restrict__ ubias, const float* __restrict__ bcat,
    float* __restrict__ Cf, u16* __restrict__ Cb, int Kdim,
    const u16* __restrict__ Xh, float* __restrict__ s0c,
    const int* __restrict__ idx, const int* __restrict__ cnts,
    const float4* __restrict__ sc4, const u16* __restrict__ HPb,
    const float* __restrict__ bb, const float* __restrict__ bm,
    const float* __restrict__ be) {
  constexpr int BROWS = (MODE == 2) ? 64 : 128;   // tile N width
  constexpr int NT = (MODE == 2) ? 2 : 4;         // per-wave 16-col tiles
  constexpr int BP = BROWS * 32;                  // B panel size (u16)
  __shared__ __align__(16) u16 As[2 * 128 * 32];
  __shared__ __align__(16) u16 Bs[2 * BP];

  const int t = threadIdx.x;
  const int lane = t & 63;
  const int wid = t >> 6;
  const int m0 = blockIdx.x * 128;
  const int n0 = blockIdx.y * BROWS;

  bool remap = false;
  if constexpr (MODE == 0) {
    const int cnt0 = cnts[0];
    if (blockIdx.y < 4) {
      if (m0 >= cnt0) return;          // group0 only
      remap = true;
    } else if (blockIdx.y >= 8) {
      if (m0 + 128 <= cnt0) return;    // group1 only
      remap = true;
    }
  }

  // two A rows + B rows staged per thread (rows r, r+64), koff chunk
  int ra0 = m0 + (t >> 2), ra1 = m0 + 64 + (t >> 2);
  if (MODE == 0 && remap) { ra0 = idx[ra0]; ra1 = idx[ra1]; }
  const int rb0 = n0 + (t >> 2), rb1 = n0 + 64 + (t >> 2);
  const int koff = (t & 3) * 8;
  const int lds0 = (t >> 2) * 32 + koff;       // rows 0..63 panel slot
  const int lds1 = 2048 + lds0;                // rows 64..127

  const int wm = (wid & 1) * 64;
  const int wn = (wid >> 1) * (NT * 16);
  const int fr = lane & 15;
  const int kq = (lane >> 4) * 8;

  f32x4 acc[4][NT];
#pragma unroll
  for (int i = 0; i < 4; i++)
#pragma unroll
    for (int j = 0; j < NT; j++) acc[i][j] = (f32x4){0.f, 0.f, 0.f, 0.f};

  for (int k0 = 0; k0 < Kdim; k0 += 64) {
    __syncthreads();
#pragma unroll
    for (int pn = 0; pn < 2; pn++) {
      const int kb = k0 + pn * 32 + koff;
      gl2lds(&A[(size_t)ra0 * Kdim + kb], &As[pn * 4096 + lds0]);
      gl2lds(&A[(size_t)ra1 * Kdim + kb], &As[pn * 4096 + lds1]);
      gl2lds(&Bt[(size_t)rb0 * Kdim + kb], &Bs[pn * BP + lds0]);
      if constexpr (BROWS == 128)
        gl2lds(&Bt[(size_t)rb1 * Kdim + kb], &Bs[pn * BP + lds1]);
    }
    __syncthreads();
#pragma unroll
    for (int pn = 0; pn < 2; pn++) {
      f16x8 av[4], bv[NT];
#pragma unroll
      for (int i = 0; i < 4; i++)
        av[i] = *(const f16x8*)&As[pn * 4096 + (wm + i * 16 + fr) * 32 + kq];
#pragma unroll
      for (int j = 0; j < NT; j++)
        bv[j] = *(const f16x8*)&Bs[pn * BP + (wn + j * 16 + fr) * 32 + kq];
#pragma unroll
      for (int mt = 0; mt < 4; mt++)
#pragma unroll
        for (int nt = 0; nt < NT; nt++)
          acc[mt][nt] = __builtin_amdgcn_mfma_f32_16x16x32_f16(
              av[mt], bv[nt], acc[mt][nt], 0, 0, 0);
    }
  }

  const int r0 = (lane >> 4) * 4;
  if constexpr (MODE == 0) {
    if (blockIdx.y < 4) {
      float pl[4][4];
      int xrow[4][4];
#pragma unroll
      for (int mt = 0; mt < 4; mt++)
#pragma unroll
        for (int r = 0; r < 4; r++) {
          pl[mt][r] = 0.f;
          xrow[mt][r] = idx[m0 + wm + mt * 16 + r0 + r];
        }
#pragma unroll
      for (int mt = 0; mt < 4; mt++)
#pragma unroll
        for (int nt = 0; nt < 4; nt++) {
          int col = n0 + wn + nt * 16 + fr;
          float bv2 = ubias[col];
#pragma unroll
          for (int r = 0; r < 4; r++)
            pl[mt][r] += (acc[mt][nt][r] + bv2) *
                         h2f(Xh[(size_t)xrow[mt][r] * 512 + col]);
        }
#pragma unroll
      for (int mt = 0; mt < 4; mt++)
#pragma unroll
        for (int r = 0; r < 4; r++) {
          float p = pl[mt][r];
          p += __shfl_xor(p, 1);
          p += __shfl_xor(p, 2);
          p += __shfl_xor(p, 4);
          p += __shfl_xor(p, 8);
          if (fr == r) {
            int slot = m0 + wm + mt * 16 + r0 + r;
            atomicAdd(&s0c[slot], p);
          }
        }
      return;
    }
    if (blockIdx.y < 8) {
#pragma unroll
      for (int mt = 0; mt < 4; mt++)
#pragma unroll
        for (int nt = 0; nt < 4; nt++) {
          int col = n0 - 512 + wn + nt * 16 + fr;
          float bv2 = bcat[col];
#pragma unroll
          for (int r = 0; r < 4; r++) {
            int row = m0 + wm + mt * 16 + r0 + r;
            Cb[(size_t)row * 1408 + col] = f2h(acc[mt][nt][r] + bv2);
          }
        }
    } else {
#pragma unroll
      for (int mt = 0; mt < 4; mt++)
#pragma unroll
        for (int nt = 0; nt < 4; nt++) {
          int pcol = n0 - 1024 + wn + nt * 16 + fr;
          float bv2 = bcat[512 + pcol];
#pragma unroll
          for (int r = 0; r < 4; r++) {
            int slot = m0 + wm + mt * 16 + r0 + r;
            Cb[(size_t)slot * 1408 + 512 + pcol] = f2h(acc[mt][nt][r] + bv2);
          }
        }
    }
  } else {
#pragma unroll
    for (int mt = 0; mt < 4; mt++)
#pragma unroll
      for (int nt = 0; nt < NT; nt++) {
        int col = n0 + wn + nt * 16 + fr;
        float b0 = bb[512 + col];
        float b1 = bm[512 + col];
        float b2 = be[512 + col];
#pragma unroll
        for (int r = 0; r < 4; r++) {
          int row = m0 + wm + mt * 16 + r0 + r;
          float4 s = sc4[row];
          float hv = h2f(HPb[(size_t)row * 1408 + col]);
          Cf[(size_t)row * 512 + col] =
              s.x * hv + s.y * b0 + s.z * b1 + s.w * b2 + acc[mt][nt][r];
        }
      }
  }
}

// ---------------- fused gather / scores / softmax / aggregate ---------------
__global__ __launch_bounds__(256) void attn_kernel(
    const int* __restrict__ masks, const int* __restrict__ begins,
    const int* __restrict__ blens, const int* __restrict__ middles,
    const int* __restrict__ mlens, const int* __restrict__ ends,
    const int* __restrict__ elens, const float* __restrict__ emb,
    const u16* __restrict__ HPb, const float* __restrict__ lmr,
    const float* __restrict__ s0buf, const float* __restrict__ cbuf,
    const int* __restrict__ perm, float4* __restrict__ sc4,
    u16* __restrict__ Ebar) {
  const int t = threadIdx.x;
  const int lane = t & 63;
  const int wid = t >> 6;
  const int pos = blockIdx.x * 4 + wid;
  const int mask = masks[pos];
  const int slot = perm[pos];
  u16* erow = Ebar + (size_t)pos * 768;

  int l0 = min(blens[pos], 5), l1 = min(mlens[pos], 5), l2 = min(elens[pos], 5);
  int nv = l0 + l1 + l2;

  if (mask == 0) {
    float s0 = s0buf[slot] + cbuf[0];
    int ninv = 15 - nv;
    float w0;
    if (ninv == 0) {
      w0 = 1.f;
    } else {
      float Mx = fmaxf(s0, 0.f);
      float e0 = __expf(s0 - Mx);
      w0 = e0 / (e0 + (float)ninv * __expf(-Mx));
    }
    if (lane == 0) sc4[pos] = make_float4(w0, 0.f, 0.f, 0.f);
    ushort4 zz; zz.x = zz.y = zz.z = zz.w = 0;
    *(ushort4*)(erow + 0 * 256 + lane * 4) = zz;
    *(ushort4*)(erow + 1 * 256 + lane * 4) = zz;
    *(ushort4*)(erow + 2 * 256 + lane * 4) = zz;
  } else {
    const int s = pos & (SS - 1);
    float g[3];
    if (s == 0 || s == SS - 1) {
      g[0] = 1.f; g[1] = 0.f; g[2] = 1.f;
    } else {
      const float* p0 = lmr + (size_t)(pos - 1) * 9;
      const float* p1 = lmr + (size_t)pos * 9;
      const float* p2 = lmr + (size_t)(pos + 1) * 9;
      g[0] = sigm(p0[0] + p1[3] + p2[6]);
      g[1] = sigm(p0[1] + p1[4] + p2[7]);
      g[2] = sigm(p0[2] + p1[5] + p2[8]);
    }
    const bool deg = (nv == 15);
    int l[3] = {l0, l1, l2};
    if (deg) { l[0] = 0; l[1] = 0; l[2] = 0; }

    float4 Pt[3];
    float qb[3];
    if (!deg) {
      const u16* prow = HPb + (size_t)slot * 1408 + 512;
#pragma unroll
      for (int ty = 0; ty < 3; ty++) {
        ushort4 pu = *(const ushort4*)(prow + ty * 256 + lane * 4);
        Pt[ty].x = h2f(pu.x); Pt[ty].y = h2f(pu.y);
        Pt[ty].z = h2f(pu.z); Pt[ty].w = h2f(pu.w);
        qb[ty] = h2f(prow[768 + ty]);
      }
    }
    const int* idxp[3];
    idxp[0] = begins + (size_t)pos * 5;
    idxp[1] = middles + (size_t)pos * 5;
    idxp[2] = ends + (size_t)pos * 5;

    float4 ev[3][5];
    float scv[3][5];
    float Mx = deg ? 0.f : -3.0e38f;
#pragma unroll
    for (int ty = 0; ty < 3; ty++) {
#pragma unroll
      for (int w = 0; w < 5; w++) {
        bool act = (w >= l[ty]);      // wave-uniform
        if (act) {
          ev[ty][w] = *(const float4*)(emb + (size_t)idxp[ty][w] * 256 + lane * 4);
          float sv = 0.f;
          if (!deg) {
            float4 e = ev[ty][w];
            float d = Pt[ty].x * e.x + Pt[ty].y * e.y + Pt[ty].z * e.z + Pt[ty].w * e.w;
#pragma unroll
            for (int o = 32; o > 0; o >>= 1) d += __shfl_xor(d, o);
            sv = g[ty] * (d + qb[ty]);
          }
          scv[ty][w] = sv;
          Mx = fmaxf(Mx, sv);
        }
      }
    }
    float wts0 = deg ? 1.f : 0.f;     // hidden survives only in deg case
    float zs = wts0;
    float wts[3][5];
#pragma unroll
    for (int ty = 0; ty < 3; ty++)
#pragma unroll
      for (int w = 0; w < 5; w++) {
        bool act = (w >= l[ty]);
        float wv = act ? __expf(scv[ty][w] - Mx) : 0.f;
        wts[ty][w] = wv;
        zs += wv;
      }
    float inv = 1.f / zs;
    float alpha[3];
#pragma unroll
    for (int ty = 0; ty < 3; ty++) {
      float ax = 0.f, ay = 0.f, az = 0.f, aw = 0.f, asum = 0.f;
#pragma unroll
      for (int w = 0; w < 5; w++) {
        if (w >= l[ty]) {
          float wk = wts[ty][w];
          asum += wk;
          ax += wk * ev[ty][w].x;
          ay += wk * ev[ty][w].y;
          az += wk * ev[ty][w].z;
          aw += wk * ev[ty][w].w;
        }
      }
      float sg = g[ty] * inv;
      alpha[ty] = sg * asum;
      ushort4 h;
      h.x = f2h(ax * sg); h.y = f2h(ay * sg); h.z = f2h(az * sg); h.w = f2h(aw * sg);
      *(ushort4*)(erow + ty * 256 + lane * 4) = h;
    }
    if (lane == 0) sc4[pos] = make_float4(wts0 * inv, alpha[0], alpha[1], alpha[2]);
  }
}

// ---------------------------------------------------------------------------
extern "C" void kernel_launch(void* const* d_in, const int* in_sizes, int n_in,
                              void* d_out, int out_size, void* d_ws, size_t ws_size,
                              hipStream_t stream) {
  const float* hiddens = (const float*)d_in[0];
  const int* masks = (const int*)d_in[1];
  const int* begins = (const int*)d_in[2];
  const int* blens = (const int*)d_in[3];
  const int* middles = (const int*)d_in[4];
  const int* mlens = (const int*)d_in[5];
  const int* ends = (const int*)d_in[6];
  const int* elens = (const int*)d_in[7];
  const float* emb = (const float*)d_in[8];
  const float* Wh = (const float*)d_in[9];
  const float* bh = (const float*)d_in[10];
  const float* Wb = (const float*)d_in[11];
  const float* bb = (const float*)d_in[12];
  const float* Wm = (const float*)d_in[13];
  const float* bm = (const float*)d_in[14];
  const float* We = (const float*)d_in[15];
  const float* be = (const float*)d_in[16];
  const float* Wg = (const float*)d_in[17];
  const float* bg = (const float*)d_in[18];
  float* out = (float*)d_out;

  char* ws = (char*)d_ws;
  size_t off = 0;
  auto alloc = [&](size_t bytes) -> char* {
    char* p = ws + off;
    off += (bytes + 255) & ~(size_t)255;
    return p;
  };
  u16* Xh = (u16*)alloc((size_t)8192 * 512 * 2);
  u16* Breg = (u16*)alloc((size_t)1920 * 512 * 2);   // [M | WhvT | Wcomb]
  u16* WvT = (u16*)alloc((size_t)512 * 768 * 2);
  u16* HPb = (u16*)alloc((size_t)8192 * 1408 * 2);   // [hv fp16 | P fp16]
  float* lmr = (float*)alloc((size_t)8192 * 9 * 4);
  float* s0c = (float*)alloc((size_t)8192 * 4);
  float* bcat = (float*)alloc((size_t)1408 * 4);
  float* u = (float*)alloc((size_t)512 * 4);
  float* cbuf = (float*)alloc((size_t)4);
  float* sc4 = (float*)alloc((size_t)8192 * 4 * 4);
  u16* Ebar = (u16*)alloc((size_t)8192 * 768 * 2);
  int* idx = (int*)alloc((size_t)8192 * 4);
  int* perm = (int*)alloc((size_t)8192 * 4);
  int* cnts = (int*)alloc((size_t)256);
  if (off > ws_size) return;  // fail loudly (output stays poisoned)

  // 0) zero partition counters
  hipMemsetAsync(cnts, 0, 8, stream);
  // 1) all preps + gemmA in one launch
  prep_all<<<1236, 256, 0, stream>>>(hiddens, Wg, bg, Wh, Wb, Wm, We, bb, bm, be,
                                     bh, masks, Xh, lmr, s0c, Breg, WvT, bcat,
                                     u, cbuf, idx, perm, cnts);
  // 2) gemmB: y<4 -> s0 (group0); y4-7 -> hv (all); y>=8 -> P (group1)
  gemm_k<0><<<dim3(64, 15), 256, 0, stream>>>(
      Xh, Breg, u, bcat, nullptr, HPb, 512, Xh, s0c, idx, cnts,
      nullptr, nullptr, nullptr, nullptr, nullptr);
  // 3) fused attention -> sc4 + Ebar
  attn_kernel<<<2048, 256, 0, stream>>>(masks, begins, blens, middles, mlens,
                                        ends, elens, emb, HPb, lmr, s0c, cbuf,
                                        perm, (float4*)sc4, Ebar);
  // 4) gemmC: out = sc4 epilogue + Ebar @ WvT^T  (128x64 tiles, 2 blocks/CU)
  gemm_k<2><<<dim3(64, 8), 256, 0, stream>>>(
      Ebar, WvT, nullptr, nullptr, out, nullptr, 768, nullptr, nullptr,
      nullptr, nullptr, (const float4*)sc4, HPb, bb, bm, be);
}